// Round 15
// baseline (28.709 us; speedup 1.0000x reference)
//
#include <hip/hip_runtime.h>
#include <hip/hip_bf16.h>

typedef __bf16 bf16x8 __attribute__((ext_vector_type(8)));
typedef float  f32x4  __attribute__((ext_vector_type(4)));

#define B_ROWS 8192
#define IN_DIM 256
#define OUT_DIM 32
#define NCLS 50
#define INV_T (1.0f / 0.6f)

#define CVT_BLOCKS 1024  // x cvt: 8192*256 / (256*8)
#define ROWTILES 16      // 8192 / 512 rows per block
#define NSUB 16          // 128 rows/wave = 8 chunks = 16 half-K sub-chunks

__device__ __forceinline__ void gload_lds16(const void* g, void* l) {
    __builtin_amdgcn_global_load_lds(
        (const __attribute__((address_space(1))) void*)g,
        (__attribute__((address_space(3))) void*)l, 16, 0, 0);
}

// prep (r14 verbatim): blocks [0,50) W-class; blocks [50,1074) x cvt.
__global__ __launch_bounds__(256) void prep(const float* __restrict__ x,
                                            const float* __restrict__ w,
                                            __bf16* __restrict__ xb,
                                            __bf16* __restrict__ wb) {
    __shared__ float wm[4];
    int bid = blockIdx.x;
    if (bid < NCLS) {
        int c = bid;
        int i = threadIdx.x;
        const float* wc = w + (size_t)c * OUT_DIM * IN_DIM + i;
        float wv[OUT_DIM];
#pragma unroll
        for (int o = 0; o < OUT_DIM; ++o) wv[o] = wc[o * IN_DIM];
        float gsum = 0.f;
#pragma unroll
        for (int o = 0; o < OUT_DIM; ++o) gsum += fabsf(wv[o]);
        float m = gsum;
#pragma unroll
        for (int s = 1; s < 64; s <<= 1) m = fmaxf(m, __shfl_xor(m, s));
        if ((threadIdx.x & 63) == 0) wm[threadIdx.x >> 6] = m;
        __syncthreads();
        m = fmaxf(fmaxf(wm[0], wm[1]), fmaxf(wm[2], wm[3]));
        float an = __expf((gsum - m) * INV_T);
        __bf16* wo = wb + (size_t)c * OUT_DIM * IN_DIM + i;
#pragma unroll
        for (int o = 0; o < OUT_DIM; ++o)
            wo[o * IN_DIM] = (__bf16)(wv[o] * an);
    } else {
        int i = ((bid - NCLS) * 256 + threadIdx.x) * 8;
        float4 v0 = *reinterpret_cast<const float4*>(x + i);
        float4 v1 = *reinterpret_cast<const float4*>(x + i + 4);
        bf16x8 r;
        r[0] = (__bf16)v0.x; r[1] = (__bf16)v0.y; r[2] = (__bf16)v0.z; r[3] = (__bf16)v0.w;
        r[4] = (__bf16)v1.x; r[5] = (__bf16)v1.y; r[6] = (__bf16)v1.z; r[7] = (__bf16)v1.w;
        *reinterpret_cast<bf16x8*>(xb + i) = r;
    }
}

// GEMM: out[b,c,o] = sum_i xb[b,i]*wb[c,o,i] + bias[c,o]
// grid = 25 pairs * 16 row-tiles. Wave = 128 rows, 2 classes.
// Half-K sub-chunk pipeline: sub-chunk = 16 rows x 128 K = 4 KB; 4 bufs/wave
// (16 KB; block 64 KB -> 2 blocks/CU); prefetch depth 3 sub-chunks (~covers
// L3 latency). Acc carries across the 2 halves of each chunk.
// Static vmcnt table (loads 4/iter; 4 stores after odd iters), fully unrolled.
// Swizzle (both sides): within a 16-slot (256B) row, phys slot p of row r
// holds logical slot p^r. W slab: 512B rows, phys s31 holds s31^(r&15).
__global__ __launch_bounds__(256, 2) void gemm(const __bf16* __restrict__ xb,
                                               const __bf16* __restrict__ wb,
                                               const float* __restrict__ bias,
                                               float* __restrict__ out) {
    __shared__ __align__(16) char lds[4 * 4 * 4096];  // 4 waves * 4 bufs * 4 KB

    int bid = blockIdx.x;
    int cp = bid >> 4;
    int rt = bid & (ROWTILES - 1);
    int c0 = cp * 2;
    int row0 = rt * 512;
    int lane = threadIdx.x & 63;
    int w4 = threadIdx.x >> 6;
    int l15 = lane & 15;
    int g = lane >> 4;
    int s31 = lane & 31;
    int lr = lane >> 5;
    int row4 = lane >> 4;        // A-stage: sub-row within instr
    int p15 = lane & 15;         // A-stage: phys slot

    char* wavelds = lds + w4 * 16384;

    // --- stage W' pair (32 KB, 64 rows x 512 B) into lds[0..32K) ---
    const char* wsrc = (const char*)(wb + (size_t)c0 * OUT_DIM * IN_DIM);
#pragma unroll
    for (int jw = 0; jw < 8; ++jw) {
        int re = jw * 8 + w4 * 2;
        int r = re + lr;
        gload_lds16(wsrc + (size_t)r * 512 + ((s31 ^ (r & 15)) * 16),
                    lds + re * 512);
    }
    // bias (completes under the same drain)
    f32x4 bv00 = *reinterpret_cast<const f32x4*>(bias + c0 * OUT_DIM + g * 4);
    f32x4 bv01 = *reinterpret_cast<const f32x4*>(bias + c0 * OUT_DIM + 16 + g * 4);
    f32x4 bv10 = *reinterpret_cast<const f32x4*>(bias + (c0 + 1) * OUT_DIM + g * 4);
    f32x4 bv11 = *reinterpret_cast<const f32x4*>(bias + (c0 + 1) * OUT_DIM + 16 + g * 4);

    asm volatile("s_waitcnt vmcnt(0)" ::: "memory");
    __syncthreads();
    __builtin_amdgcn_sched_barrier(0);

    // --- W' -> 128 pinned VGPRs (swizzled ds_read) ---
    bf16x8 W[2][16];
#pragma unroll
    for (int ci = 0; ci < 2; ++ci)
#pragma unroll
        for (int kk = 0; kk < 8; ++kk) {
            int wr1 = ci * 32 + l15;
            int wr2 = wr1 + 16;
            W[ci][kk]     = *reinterpret_cast<const bf16x8*>(
                lds + (size_t)wr1 * 512 + (((4 * kk + g) ^ l15) * 16));
            W[ci][8 + kk] = *reinterpret_cast<const bf16x8*>(
                lds + (size_t)wr2 * 512 + (((4 * kk + g) ^ l15) * 16));
        }
#pragma unroll
    for (int ci = 0; ci < 2; ++ci)
#pragma unroll
        for (int kk = 0; kk < 16; ++kk)
            asm volatile("" : "+v"(W[ci][kk]));
    asm volatile("" : "+v"(bv00), "+v"(bv01), "+v"(bv10), "+v"(bv11));
    __builtin_amdgcn_sched_barrier(0);
    __syncthreads();   // all waves done reading W before A staging overwrites

    // --- A sub-chunk pipeline ---
    const char* arows = (const char*)(xb + (size_t)(row0 + w4 * 128) * IN_DIM);
    // per-lane src offsets for the 4 stage instrs: row_l = j*4+row4,
    // logical slot = p15 ^ row_l (within the 256B half-row)
    float* orow = out + (size_t)(row0 + w4 * 128 + l15) * (NCLS * OUT_DIM) + c0 * OUT_DIM + g * 4;

#define STAGE_SC(SC)                                                               \
    _Pragma("unroll") for (int j = 0; j < 4; ++j) {                                \
        int rl = j * 4 + row4;                                                     \
        gload_lds16(arows + (size_t)((SC) >> 1) * 8192 + ((SC) & 1) * 256          \
                        + (size_t)rl * 512 + ((p15 ^ rl) * 16),                    \
                    wavelds + ((SC) & 3) * 4096 + j * 1024);                       \
    }
#define VMW(N) asm volatile("s_waitcnt vmcnt(" #N ")" ::: "memory")

    STAGE_SC(0)
    STAGE_SC(1)
    STAGE_SC(2)

    f32x4 acc00, acc01, acc10, acc11;

#pragma unroll
    for (int sc = 0; sc < NSUB; ++sc) {
        if (sc <= 12) STAGE_SC(sc + 3)
        // exact issued-after counts (4 loads/iter; 4 stores after odd iters)
        if (sc <= 1)       VMW(12);
        else if (sc == 2)  VMW(16);
        else if (sc <= 12) { if (sc & 1) VMW(16); else VMW(20); }
        else if (sc <= 14) VMW(12);
        else               VMW(4);
        __builtin_amdgcn_sched_barrier(0);

        if (!(sc & 1)) { acc00 = bv00; acc01 = bv01; acc10 = bv10; acc11 = bv11; }
        char* buf = wavelds + (sc & 3) * 4096;
        int h4 = (sc & 1) * 4;
#pragma unroll
        for (int kkl = 0; kkl < 4; ++kkl) {
            bf16x8 a = *reinterpret_cast<const bf16x8*>(
                buf + (size_t)l15 * 256 + (((4 * kkl + g) ^ l15) * 16));
            acc00 = __builtin_amdgcn_mfma_f32_16x16x32_bf16(W[0][h4 + kkl],     a, acc00, 0, 0, 0);
            acc01 = __builtin_amdgcn_mfma_f32_16x16x32_bf16(W[0][8 + h4 + kkl], a, acc01, 0, 0, 0);
            acc10 = __builtin_amdgcn_mfma_f32_16x16x32_bf16(W[1][h4 + kkl],     a, acc10, 0, 0, 0);
            acc11 = __builtin_amdgcn_mfma_f32_16x16x32_bf16(W[1][8 + h4 + kkl], a, acc11, 0, 0, 0);
        }
        if (sc & 1) {
            float* op = orow + (size_t)(sc >> 1) * 16 * (NCLS * OUT_DIM);
            *reinterpret_cast<f32x4*>(op) = acc00;
            *reinterpret_cast<f32x4*>(op + 16) = acc01;
            *reinterpret_cast<f32x4*>(op + OUT_DIM) = acc10;
            *reinterpret_cast<f32x4*>(op + OUT_DIM + 16) = acc11;
        }
    }
#undef STAGE_SC
#undef VMW
}

extern "C" void kernel_launch(void* const* d_in, const int* in_sizes, int n_in,
                              void* d_out, int out_size, void* d_ws, size_t ws_size,
                              hipStream_t stream) {
    const float* x    = (const float*)d_in[0];
    const float* w    = (const float*)d_in[1];
    const float* bias = (const float*)d_in[2];
    float* out = (float*)d_out;

    __bf16* xb = (__bf16*)d_ws;                      // 8192*256 bf16 = 4 MB
    __bf16* wb = xb + (size_t)B_ROWS * IN_DIM;       // 50*32*256 bf16 = 0.8 MB

    prep<<<NCLS + CVT_BLOCKS, 256, 0, stream>>>(x, w, xb, wb);
    gemm<<<25 * ROWTILES, 256, 0, stream>>>(xb, wb, bias, out);
}